// Round 4
// baseline (744.275 us; speedup 1.0000x reference)
//
#include <hip/hip_runtime.h>
#include <cstdint>

typedef unsigned short u16;
typedef __attribute__((ext_vector_type(8))) short short8;
typedef __attribute__((ext_vector_type(4))) float floatx4;

#define S_LEN 1024
#define BATCH 64
#define EDIM 1024
#define UDIM 1024
#define VOCAB 32000
#define MTOT (BATCH * S_LEN)   // 65536
#define NTOT (3 * UDIM)        // 3072

__device__ __forceinline__ u16 f2bf(float x) {
  unsigned u = __float_as_uint(x);
  return (u16)((u + 0x7fffu + ((u >> 16) & 1u)) >> 16);  // RNE, inputs are finite
}

// async global->LDS, 16B per lane. LDS dest must be wave-uniform base + lane*16.
__device__ __forceinline__ void async16(const u16* g, u16* s) {
  __builtin_amdgcn_global_load_lds(
      (__attribute__((address_space(1))) void*)(uintptr_t)g,
      (__attribute__((address_space(3))) void*)(uintptr_t)s,
      16, 0, 0);
}

__device__ __forceinline__ float sigm(float x) {
  return __builtin_amdgcn_rcpf(1.f + __expf(-x));
}

// ---------------- convert emb fp32 -> bf16 ----------------
__global__ __launch_bounds__(256) void conv_emb(const float4* __restrict__ in,
                                                ushort4* __restrict__ out, long n4) {
  long i = (long)blockIdx.x * 256 + threadIdx.x;
  if (i >= n4) return;
  float4 v = in[i];
  ushort4 o;
  o.x = f2bf(v.x); o.y = f2bf(v.y); o.z = f2bf(v.z); o.w = f2bf(v.w);
  out[i] = o;
}

// ------- transpose+convert W[E,U] fp32 -> Wt[U,E] bf16, 3 mats concat -------
__global__ __launch_bounds__(256) void conv_wt(const float* __restrict__ Wf,
                                               const float* __restrict__ Wi,
                                               const float* __restrict__ Wh,
                                               u16* __restrict__ wtB) {
  __shared__ float t[32][33];
  const float* W = (blockIdx.z == 0) ? Wf : ((blockIdx.z == 1) ? Wi : Wh);
  int bx = blockIdx.x * 32;  // n (input col)
  int by = blockIdx.y * 32;  // k (input row)
  int tx = threadIdx.x, ty = threadIdx.y;
  for (int j = 0; j < 32; j += 8)
    t[ty + j][tx] = W[(size_t)(by + ty + j) * UDIM + bx + tx];
  __syncthreads();
  u16* out = wtB + (size_t)blockIdx.z * UDIM * EDIM;
  for (int j = 0; j < 32; j += 8)
    out[(size_t)(bx + ty + j) * EDIM + by + tx] = f2bf(t[tx][ty + j]);
}

// ---- fused gather + 3-gate GEMM + in-register 128-step chunk scan ----
// Block: m-tile = 128 rows = one (batch b, chunk c) of 128 timesteps;
//        n-tile = 64 u-columns x 3 gates (f, i, h~) = 192 B-rows.
// Wave w owns u-cols u0 + w*16 + fr for ALL 128 t: acc[mt=0..7][gate=0..2].
// Chunk summary (F = prod f_n, G = scan from 0) computed in-register.
// launch_bounds(256,4): 4 blocks/CU (LDS 4x40KB = the full 160 KiB pool,
// VGPR cap 128 >= 80 used) -> cross-block overlap of barrier drains.
__global__ __launch_bounds__(256, 4) void gemm_scan(
    const int* __restrict__ sent, const u16* __restrict__ embB,
    const u16* __restrict__ wtB,
    const float* __restrict__ bfp, const float* __restrict__ bip,
    const float* __restrict__ bhp,
    float* __restrict__ Fc, float* __restrict__ Gc) {
  __shared__ __align__(16) u16 As[128 * 64];  // 16 KB
  __shared__ __align__(16) u16 Bs[192 * 64];  // 24 KB

  const int tid = threadIdx.x;
  const int wave = tid >> 6;
  const int lane = tid & 63;

  // XCD-aware swizzle (XCD = bid%8 round-robin): per XCD, slots iterate
  // mtile-inner(16) x utile-outer(16) supertiles -> 16 A-tiles (4 MB) stay
  // ~L2-resident across 256 slots; each B-tile (384 KB) fetched once per
  // 16-slot window. Cuts cross-XCD tile replication in the private L2s.
  const int g = blockIdx.x;
  const int x = g & 7;              // XCD
  const int s = g >> 3;             // 0..1023 slot within XCD
  const int sup = s >> 8;           // 0..3 supertile
  const int utile = (s >> 4) & 15;  // u-tile (outer)
  const int ml = s & 15;            // mtile local (inner)
  const int mtile = (sup * 16 + ml) * 8 + x;  // 0..511, bijective
  const int m0 = mtile * 128;
  const int u0 = utile * 64;

  // staging maps, XOR-swizzled at 16B-chunk granularity: slot (row r, chunk c)
  // holds global chunk c^(r&7) -> conflict-free ds_read_b128 on the read side.
  const u16* gA[4]; int loA[4];
  const u16* gB[6]; int loB[6];
#pragma unroll
  for (int j = 0; j < 4; ++j) {
    int idx = j * 256 + tid;
    int r = idx >> 3;
    int cg = (idx & 7) ^ (r & 7);
    int tok = sent[m0 + r];
    gA[j] = embB + (size_t)tok * EDIM + cg * 8;
    loA[j] = idx * 8;
  }
#pragma unroll
  for (int j = 0; j < 6; ++j) {
    int idx = j * 256 + tid;
    int r = idx >> 3;                            // 0..191
    int gr = (r >> 6) * UDIM + u0 + (r & 63);    // gate*1024 + u
    int cg = (idx & 7) ^ (r & 7);
    gB[j] = wtB + (size_t)gr * EDIM + cg * 8;
    loB[j] = idx * 8;
  }

  floatx4 acc[8][3] = {};
  const int fr = lane & 15;
  const int fq = lane >> 4;
  const int fr7 = fr & 7;
  const int un = wave * 16 + fr;  // u-col within block's 64

  for (int k0 = 0; k0 < EDIM; k0 += 64) {
#pragma unroll
    for (int j = 0; j < 4; ++j) async16(gA[j] + k0, &As[loA[j]]);
#pragma unroll
    for (int j = 0; j < 6; ++j) async16(gB[j] + k0, &Bs[loB[j]]);
    __syncthreads();
#pragma unroll
    for (int kk = 0; kk < 2; ++kk) {
      const int swz = ((kk * 4 + fq) ^ fr7) * 8;
      short8 b0 = *(const short8*)&Bs[(0 * 64 + un) * 64 + swz];
      short8 b1 = *(const short8*)&Bs[(1 * 64 + un) * 64 + swz];
      short8 b2 = *(const short8*)&Bs[(2 * 64 + un) * 64 + swz];
#pragma unroll
      for (int mt = 0; mt < 8; ++mt) {
        short8 am = *(const short8*)&As[(mt * 16 + fr) * 64 + swz];
        acc[mt][0] = __builtin_amdgcn_mfma_f32_16x16x32_bf16(am, b0, acc[mt][0], 0, 0, 0);
        acc[mt][1] = __builtin_amdgcn_mfma_f32_16x16x32_bf16(am, b1, acc[mt][1], 0, 0, 0);
        acc[mt][2] = __builtin_amdgcn_mfma_f32_16x16x32_bf16(am, b2, acc[mt][2], 0, 0, 0);
      }
    }
    __syncthreads();
  }

  // ---- epilogue: gate nonlinearity + affine chunk-scan, all in-register ----
  // C/D layout: col=lane&15 (u), row=(lane>>4)*4+reg (t within mt's 16 rows).
  // t = mt*16 + fq*4 + r. Affine map per step: h' = fn*h + g.
  const int ug = u0 + un;
  const float bfv = bfp[ug], biv = bip[ug], bhv = bhp[ug];
  float MF = 1.f, MG = 0.f;  // running chunk map
#pragma unroll
  for (int mt = 0; mt < 8; ++mt) {
    // lane-local 4-step segment (t ascending in r)
    float Fl = 1.f, Gl = 0.f;
#pragma unroll
    for (int r = 0; r < 4; ++r) {
      float fs = sigm(acc[mt][0][r] + bfv);
      float is = sigm(acc[mt][1][r] + biv);
      float hv = acc[mt][2][r] + bhv;
      float inv = __builtin_amdgcn_rcpf(fs + is);
      float fn = fs * inv;
      float g2 = is * inv * hv;
      Fl *= fn;
      Gl = fn * Gl + g2;
    }
    // inclusive Hillis-Steele scan over the 4 fq segments (t order = fq asc)
    float yF = __shfl_up(Fl, 16), yG = __shfl_up(Gl, 16);
    if (fq >= 1) { Gl = Fl * yG + Gl; Fl = yF * Fl; }
    yF = __shfl_up(Fl, 32); yG = __shfl_up(Gl, 32);
    if (fq >= 2) { Gl = Fl * yG + Gl; Fl = yF * Fl; }
    // 16-step block map = inclusive value at fq=3; compose onto running map
    float bF = __shfl(Fl, fr + 48);
    float bG = __shfl(Gl, fr + 48);
    MG = bF * MG + bG;
    MF = MF * bF;
  }
  if (fq == 0) {
    const int b = mtile >> 3, c = mtile & 7;
    Fc[c * (BATCH * UDIM) + b * UDIM + ug] = MF;
    Gc[c * (BATCH * UDIM) + b * UDIM + ug] = MG;
  }
}

// ---------------- combine chunks + MLP head ----------------
__global__ __launch_bounds__(256) void mlp_head(
    const float* __restrict__ Fc, const float* __restrict__ Gc,
    const float* __restrict__ W1, const float* __restrict__ b1,
    const float* __restrict__ W2, const float* __restrict__ b2,
    float* __restrict__ out) {
  const int b = blockIdx.x;
  const int tid = threadIdx.x;
  __shared__ float h_s[UDIM];
  __shared__ float z1[64];
  for (int u = tid; u < UDIM; u += 256) {
    float h = 0.f;
#pragma unroll
    for (int c = 0; c < 8; ++c) {
      float F = Fc[c * (BATCH * UDIM) + b * UDIM + u];
      float G = Gc[c * (BATCH * UDIM) + b * UDIM + u];
      h = F * h + G;
    }
    h_s[u] = h;
  }
  __syncthreads();
  const int j = tid >> 2, p = tid & 3;
  float partial = 0.f;
  for (int u = p * 256; u < p * 256 + 256; ++u) partial += h_s[u] * W1[u * 64 + j];
  partial += __shfl_down(partial, 1);
  partial += __shfl_down(partial, 2);
  if (p == 0) z1[j] = partial + b1[j];
  __syncthreads();
  if (tid < 64) {
    float v = z1[tid] * W2[tid];
#pragma unroll
    for (int off = 32; off > 0; off >>= 1) v += __shfl_down(v, off);
    if (tid == 0) out[b] = 1.f / (1.f + __expf(-(v + b2[0])));
  }
}

extern "C" void kernel_launch(void* const* d_in, const int* in_sizes, int n_in,
                              void* d_out, int out_size, void* d_ws, size_t ws_size,
                              hipStream_t stream) {
  const int* sent = (const int*)d_in[0];
  const float* emb = (const float*)d_in[1];
  const float* Wf = (const float*)d_in[2];
  const float* bf_ = (const float*)d_in[3];
  const float* Wi = (const float*)d_in[4];
  const float* bi_ = (const float*)d_in[5];
  const float* Wh = (const float*)d_in[6];
  const float* bh_ = (const float*)d_in[7];
  const float* W1 = (const float*)d_in[8];
  const float* b1 = (const float*)d_in[9];
  const float* W2 = (const float*)d_in[10];
  const float* b2 = (const float*)d_in[11];
  float* out = (float*)d_out;

  // workspace layout (~76 MiB)
  char* ws = (char*)d_ws;
  u16* embB = (u16*)ws;   ws += (size_t)VOCAB * EDIM * 2;       // 65,536,000
  u16* wtB = (u16*)ws;    ws += (size_t)NTOT * EDIM * 2;        //  6,291,456
  float* Fc = (float*)ws; ws += (size_t)8 * BATCH * UDIM * 4;   //  2,097,152
  float* Gc = (float*)ws; ws += (size_t)8 * BATCH * UDIM * 4;   //  2,097,152

  long n4 = (long)VOCAB * EDIM / 4;
  hipLaunchKernelGGL(conv_emb, dim3((unsigned)(n4 / 256)), dim3(256), 0, stream,
                     (const float4*)emb, (ushort4*)embB, n4);
  hipLaunchKernelGGL(conv_wt, dim3(32, 32, 3), dim3(32, 8), 0, stream, Wf, Wi, Wh, wtB);
  hipLaunchKernelGGL(gemm_scan, dim3((MTOT / 128) * (UDIM / 64)), dim3(256), 0, stream,
                     sent, embB, wtB, bf_, bi_, bh_, Fc, Gc);
  hipLaunchKernelGGL(mlp_head, dim3(BATCH), dim3(256), 0, stream, Fc, Gc, W1, b1, W2, b2, out);
}

// Round 5
// 588.465 us; speedup vs baseline: 1.2648x; 1.2648x over previous
//
#include <hip/hip_runtime.h>
#include <cstdint>

typedef unsigned short u16;
typedef __attribute__((ext_vector_type(8))) short short8;
typedef __attribute__((ext_vector_type(4))) float floatx4;

#define S_LEN 1024
#define BATCH 64
#define EDIM 1024
#define UDIM 1024
#define VOCAB 32000
#define MTOT (BATCH * S_LEN)   // 65536
#define NTOT (3 * UDIM)        // 3072

__device__ __forceinline__ u16 f2bf(float x) {
  unsigned u = __float_as_uint(x);
  return (u16)((u + 0x7fffu + ((u >> 16) & 1u)) >> 16);  // RNE, inputs are finite
}

// async global->LDS, 16B per lane. LDS dest must be wave-uniform base + lane*16.
__device__ __forceinline__ void async16(const u16* g, u16* s) {
  __builtin_amdgcn_global_load_lds(
      (__attribute__((address_space(1))) void*)(uintptr_t)g,
      (__attribute__((address_space(3))) void*)(uintptr_t)s,
      16, 0, 0);
}

__device__ __forceinline__ float sigm(float x) {
  return __builtin_amdgcn_rcpf(1.f + __expf(-x));
}

// ---------------- convert emb fp32 -> bf16 ----------------
__global__ __launch_bounds__(256) void conv_emb(const float4* __restrict__ in,
                                                ushort4* __restrict__ out, long n4) {
  long i = (long)blockIdx.x * 256 + threadIdx.x;
  if (i >= n4) return;
  float4 v = in[i];
  ushort4 o;
  o.x = f2bf(v.x); o.y = f2bf(v.y); o.z = f2bf(v.z); o.w = f2bf(v.w);
  out[i] = o;
}

// ------- transpose+convert W[E,U] fp32 -> Wt[U,E] bf16, 3 mats concat -------
__global__ __launch_bounds__(256) void conv_wt(const float* __restrict__ Wf,
                                               const float* __restrict__ Wi,
                                               const float* __restrict__ Wh,
                                               u16* __restrict__ wtB) {
  __shared__ float t[32][33];
  const float* W = (blockIdx.z == 0) ? Wf : ((blockIdx.z == 1) ? Wi : Wh);
  int bx = blockIdx.x * 32;  // n (input col)
  int by = blockIdx.y * 32;  // k (input row)
  int tx = threadIdx.x, ty = threadIdx.y;
  for (int j = 0; j < 32; j += 8)
    t[ty + j][tx] = W[(size_t)(by + ty + j) * UDIM + bx + tx];
  __syncthreads();
  u16* out = wtB + (size_t)blockIdx.z * UDIM * EDIM;
  for (int j = 0; j < 32; j += 8)
    out[(size_t)(bx + ty + j) * EDIM + by + tx] = f2bf(t[tx][ty + j]);
}

// ---- fused gather + 3-gate GEMM + in-register 128-step chunk scan ----
// Block: m-tile = 128 rows = one (batch b, chunk c) of 128 timesteps;
//        n-tile = 64 u-columns x 3 gates (f, i, h~) = 192 B-rows.
// Wave w owns u-cols u0 + w*16 + fr for ALL 128 t: acc[mt=0..7][gate=0..2].
// Chunk summary (F = prod f_n, G = scan from 0) computed in-register.
// launch_bounds(256,3): acc tile is 96 regs/lane -> (256,4)'s 128-VGPR cap
// SPILLS the accumulators (R3: WRITE_SIZE 4->151 MB, 383->585 us). 3 blocks/CU
// (<=170 VGPR) is the occupancy ceiling for this tile shape.
__global__ __launch_bounds__(256, 3) void gemm_scan(
    const int* __restrict__ sent, const u16* __restrict__ embB,
    const u16* __restrict__ wtB,
    const float* __restrict__ bfp, const float* __restrict__ bip,
    const float* __restrict__ bhp,
    float* __restrict__ Fc, float* __restrict__ Gc) {
  __shared__ __align__(16) u16 As[128 * 64];  // 16 KB
  __shared__ __align__(16) u16 Bs[192 * 64];  // 24 KB

  const int tid = threadIdx.x;
  const int wave = tid >> 6;
  const int lane = tid & 63;

  // XCD-aware swizzle (XCD = bid%8 round-robin): per XCD, slots iterate
  // mtile-inner(16) x utile-outer(16) supertiles -> 16 A-tiles (4 MB) stay
  // ~L2-resident across 256 slots; each B-tile (384 KB) fetched once per
  // 16-slot window. Cuts cross-XCD tile replication in the private L2s.
  const int g = blockIdx.x;
  const int x = g & 7;              // XCD
  const int s = g >> 3;             // 0..1023 slot within XCD
  const int sup = s >> 8;           // 0..3 supertile
  const int utile = (s >> 4) & 15;  // u-tile (outer)
  const int ml = s & 15;            // mtile local (inner)
  const int mtile = (sup * 16 + ml) * 8 + x;  // 0..511, bijective
  const int m0 = mtile * 128;
  const int u0 = utile * 64;

  // staging maps, XOR-swizzled at 16B-chunk granularity: slot (row r, chunk c)
  // holds global chunk c^(r&7) -> conflict-free ds_read_b128 on the read side.
  const u16* gA[4]; int loA[4];
  const u16* gB[6]; int loB[6];
#pragma unroll
  for (int j = 0; j < 4; ++j) {
    int idx = j * 256 + tid;
    int r = idx >> 3;
    int cg = (idx & 7) ^ (r & 7);
    int tok = sent[m0 + r];
    gA[j] = embB + (size_t)tok * EDIM + cg * 8;
    loA[j] = idx * 8;
  }
#pragma unroll
  for (int j = 0; j < 6; ++j) {
    int idx = j * 256 + tid;
    int r = idx >> 3;                            // 0..191
    int gr = (r >> 6) * UDIM + u0 + (r & 63);    // gate*1024 + u
    int cg = (idx & 7) ^ (r & 7);
    gB[j] = wtB + (size_t)gr * EDIM + cg * 8;
    loB[j] = idx * 8;
  }

  floatx4 acc[8][3] = {};
  const int fr = lane & 15;
  const int fq = lane >> 4;
  const int fr7 = fr & 7;
  const int un = wave * 16 + fr;  // u-col within block's 64

  for (int k0 = 0; k0 < EDIM; k0 += 64) {
#pragma unroll
    for (int j = 0; j < 4; ++j) async16(gA[j] + k0, &As[loA[j]]);
#pragma unroll
    for (int j = 0; j < 6; ++j) async16(gB[j] + k0, &Bs[loB[j]]);
    __syncthreads();
#pragma unroll
    for (int kk = 0; kk < 2; ++kk) {
      const int swz = ((kk * 4 + fq) ^ fr7) * 8;
      short8 b0 = *(const short8*)&Bs[(0 * 64 + un) * 64 + swz];
      short8 b1 = *(const short8*)&Bs[(1 * 64 + un) * 64 + swz];
      short8 b2 = *(const short8*)&Bs[(2 * 64 + un) * 64 + swz];
#pragma unroll
      for (int mt = 0; mt < 8; ++mt) {
        short8 am = *(const short8*)&As[(mt * 16 + fr) * 64 + swz];
        acc[mt][0] = __builtin_amdgcn_mfma_f32_16x16x32_bf16(am, b0, acc[mt][0], 0, 0, 0);
        acc[mt][1] = __builtin_amdgcn_mfma_f32_16x16x32_bf16(am, b1, acc[mt][1], 0, 0, 0);
        acc[mt][2] = __builtin_amdgcn_mfma_f32_16x16x32_bf16(am, b2, acc[mt][2], 0, 0, 0);
      }
    }
    __syncthreads();
  }

  // ---- epilogue: gate nonlinearity + affine chunk-scan, all in-register ----
  // C/D layout: col=lane&15 (u), row=(lane>>4)*4+reg (t within mt's 16 rows).
  // t = mt*16 + fq*4 + r. Affine map per step: h' = fn*h + g.
  const int ug = u0 + un;
  const float bfv = bfp[ug], biv = bip[ug], bhv = bhp[ug];
  float MF = 1.f, MG = 0.f;  // running chunk map
#pragma unroll
  for (int mt = 0; mt < 8; ++mt) {
    // lane-local 4-step segment (t ascending in r)
    float Fl = 1.f, Gl = 0.f;
#pragma unroll
    for (int r = 0; r < 4; ++r) {
      float fs = sigm(acc[mt][0][r] + bfv);
      float is = sigm(acc[mt][1][r] + biv);
      float hv = acc[mt][2][r] + bhv;
      float inv = __builtin_amdgcn_rcpf(fs + is);
      float fn = fs * inv;
      float g2 = is * inv * hv;
      Fl *= fn;
      Gl = fn * Gl + g2;
    }
    // inclusive Hillis-Steele scan over the 4 fq segments (t order = fq asc)
    float yF = __shfl_up(Fl, 16), yG = __shfl_up(Gl, 16);
    if (fq >= 1) { Gl = Fl * yG + Gl; Fl = yF * Fl; }
    yF = __shfl_up(Fl, 32); yG = __shfl_up(Gl, 32);
    if (fq >= 2) { Gl = Fl * yG + Gl; Fl = yF * Fl; }
    // 16-step block map = inclusive value at fq=3; compose onto running map
    float bF = __shfl(Fl, fr + 48);
    float bG = __shfl(Gl, fr + 48);
    MG = bF * MG + bG;
    MF = MF * bF;
  }
  if (fq == 0) {
    const int b = mtile >> 3, c = mtile & 7;
    Fc[c * (BATCH * UDIM) + b * UDIM + ug] = MF;
    Gc[c * (BATCH * UDIM) + b * UDIM + ug] = MG;
  }
}

// ---------------- combine chunks + MLP head ----------------
__global__ __launch_bounds__(256) void mlp_head(
    const float* __restrict__ Fc, const float* __restrict__ Gc,
    const float* __restrict__ W1, const float* __restrict__ b1,
    const float* __restrict__ W2, const float* __restrict__ b2,
    float* __restrict__ out) {
  const int b = blockIdx.x;
  const int tid = threadIdx.x;
  __shared__ float h_s[UDIM];
  __shared__ float z1[64];
  for (int u = tid; u < UDIM; u += 256) {
    float h = 0.f;
#pragma unroll
    for (int c = 0; c < 8; ++c) {
      float F = Fc[c * (BATCH * UDIM) + b * UDIM + u];
      float G = Gc[c * (BATCH * UDIM) + b * UDIM + u];
      h = F * h + G;
    }
    h_s[u] = h;
  }
  __syncthreads();
  const int j = tid >> 2, p = tid & 3;
  float partial = 0.f;
  for (int u = p * 256; u < p * 256 + 256; ++u) partial += h_s[u] * W1[u * 64 + j];
  partial += __shfl_down(partial, 1);
  partial += __shfl_down(partial, 2);
  if (p == 0) z1[j] = partial + b1[j];
  __syncthreads();
  if (tid < 64) {
    float v = z1[tid] * W2[tid];
#pragma unroll
    for (int off = 32; off > 0; off >>= 1) v += __shfl_down(v, off);
    if (tid == 0) out[b] = 1.f / (1.f + __expf(-(v + b2[0])));
  }
}

extern "C" void kernel_launch(void* const* d_in, const int* in_sizes, int n_in,
                              void* d_out, int out_size, void* d_ws, size_t ws_size,
                              hipStream_t stream) {
  const int* sent = (const int*)d_in[0];
  const float* emb = (const float*)d_in[1];
  const float* Wf = (const float*)d_in[2];
  const float* bf_ = (const float*)d_in[3];
  const float* Wi = (const float*)d_in[4];
  const float* bi_ = (const float*)d_in[5];
  const float* Wh = (const float*)d_in[6];
  const float* bh_ = (const float*)d_in[7];
  const float* W1 = (const float*)d_in[8];
  const float* b1 = (const float*)d_in[9];
  const float* W2 = (const float*)d_in[10];
  const float* b2 = (const float*)d_in[11];
  float* out = (float*)d_out;

  // workspace layout (~76 MiB)
  char* ws = (char*)d_ws;
  u16* embB = (u16*)ws;   ws += (size_t)VOCAB * EDIM * 2;       // 65,536,000
  u16* wtB = (u16*)ws;    ws += (size_t)NTOT * EDIM * 2;        //  6,291,456
  float* Fc = (float*)ws; ws += (size_t)8 * BATCH * UDIM * 4;   //  2,097,152
  float* Gc = (float*)ws; ws += (size_t)8 * BATCH * UDIM * 4;   //  2,097,152

  long n4 = (long)VOCAB * EDIM / 4;
  hipLaunchKernelGGL(conv_emb, dim3((unsigned)(n4 / 256)), dim3(256), 0, stream,
                     (const float4*)emb, (ushort4*)embB, n4);
  hipLaunchKernelGGL(conv_wt, dim3(32, 32, 3), dim3(32, 8), 0, stream, Wf, Wi, Wh, wtB);
  hipLaunchKernelGGL(gemm_scan, dim3((MTOT / 128) * (UDIM / 64)), dim3(256), 0, stream,
                     sent, embB, wtB, bf_, bi_, bh_, Fc, Gc);
  hipLaunchKernelGGL(mlp_head, dim3(BATCH), dim3(256), 0, stream, Fc, Gc, W1, b1, W2, b2, out);
}